// Round 8
// baseline (41.917 us; speedup 1.0000x reference)
//
#include <hip/hip_runtime.h>
#include <hip/hip_bf16.h>

// Shapes
#define B_ 64
#define L_ 64
#define D_ 512
#define F_ 32
#define H_ 512

typedef __attribute__((ext_vector_type(8))) short bf16x8;
typedef __attribute__((ext_vector_type(4))) float f32x4;

__device__ __forceinline__ float leaky(float v) { return v > 0.0f ? v : 0.01f * v; }

__device__ __forceinline__ unsigned short f2bf(float v) {
  unsigned int b = __float_as_uint(v);
  unsigned int r = b + 0x7FFF + ((b >> 16) & 1);  // RNE
  return (unsigned short)(r >> 16);
}
__device__ __forceinline__ float bf2f(unsigned short h) {
  return __uint_as_float(((unsigned int)h) << 16);
}
__device__ __forceinline__ void cvt_store4(unsigned short* ph, unsigned short* pl, float4 v) {
  ushort4 h, l;
  h.x = f2bf(v.x); l.x = f2bf(v.x - bf2f(h.x));
  h.y = f2bf(v.y); l.y = f2bf(v.y - bf2f(h.y));
  h.z = f2bf(v.z); l.z = f2bf(v.z - bf2f(h.z));
  h.w = f2bf(v.w); l.w = f2bf(v.w - bf2f(h.w));
  *(ushort4*)ph = h;
  *(ushort4*)pl = l;
}

#define GLOAD16(GP, LP)                                              \
  __builtin_amdgcn_global_load_lds(                                  \
      (const __attribute__((address_space(1))) unsigned int*)(GP),   \
      (__attribute__((address_space(3))) unsigned int*)(LP), 16, 0, 0)

// ---------------- Kernel 1: prep ----------------
// blocks [0,64):    x-split -> Xhi/Xlo [4096][512]
// blocks [64,192):  W0t split: W0t[n][k], n in [0,1024) = [Ws0 cols | Wa0 cols], k in [0,512)
// blocks [192,320): W1t split: W1t[n][k], n in [0,512), k in [0,1024) = [Ws1; Wa1]
// blocks [320,384): per-b histogram count matrix Cm[b][48][64] (counts/32, exact bf16)
__global__ __launch_bounds__(256) void prep(
    const float* __restrict__ x, const int* __restrict__ idx1,
    const int* __restrict__ idx2,
    const float* __restrict__ Ws0, const float* __restrict__ Wa0,
    const float* __restrict__ Ws1, const float* __restrict__ Wa1,
    unsigned short* __restrict__ Xhi, unsigned short* __restrict__ Xlo,
    unsigned short* __restrict__ W0thi, unsigned short* __restrict__ W0tlo,
    unsigned short* __restrict__ W1thi, unsigned short* __restrict__ W1tlo,
    unsigned short* __restrict__ Cm) {
  __shared__ __align__(16) char smem[18432 + 2304];
  const int blk = blockIdx.x;
  const int t = threadIdx.x;

  if (blk < 64) {
    const int b = blk;
    const float* src = x + (size_t)b * (L_ * D_);
    unsigned short* dh = Xhi + (size_t)b * (L_ * D_);
    unsigned short* dl = Xlo + (size_t)b * (L_ * D_);
#pragma unroll 4
    for (int i = 0; i < 32; ++i) {
      const int f4 = t + 256 * i;
      const float4 v = *(const float4*)(src + (size_t)f4 * 4);
      cvt_store4(dh + (size_t)f4 * 4, dl + (size_t)f4 * 4, v);
    }
  } else if (blk < 320) {
    // weight transpose+split
    float (*lt)[72] = (float(*)[72])smem;
    const float* src;      // [k][n-col base applied]
    unsigned short *dhi, *dlo;
    int k0, n0, ncol0, dstride;
    if (blk < 192) {  // cat0: W0t
      const int q = blk - 64;
      k0 = (q & 7) * 64;          // k in [0,512)
      n0 = (q >> 3) * 64;         // n in [0,1024)
      if (n0 < 512) { src = Ws0; ncol0 = n0; } else { src = Wa0; ncol0 = n0 - 512; }
      dhi = W0thi; dlo = W0tlo; dstride = 512;
    } else {          // cat1: W1t
      const int q = blk - 192;
      k0 = (q & 15) * 64;         // k in [0,1024)
      n0 = (q >> 4) * 64;         // n in [0,512)
      if (k0 < 512) { src = Ws1 + (size_t)k0 * H_; } else { src = Wa1 + (size_t)(k0 - 512) * H_; }
      ncol0 = n0; k0 = (blk - 192 & 15) * 64; dhi = W1thi; dlo = W1tlo; dstride = 1024;
      // note: src already offset by k-rows; below we index rows kl from it
    }
    if (blk < 192) {
#pragma unroll
      for (int i = 0; i < 4; ++i) {
        const int idx4 = t + 256 * i;
        const int kl = idx4 >> 4;
        const int n4 = (idx4 & 15) * 4;
        *(float4*)&lt[kl][n4] = *(const float4*)(src + (size_t)(k0 + kl) * H_ + ncol0 + n4);
      }
    } else {
#pragma unroll
      for (int i = 0; i < 4; ++i) {
        const int idx4 = t + 256 * i;
        const int kl = idx4 >> 4;
        const int n4 = (idx4 & 15) * 4;
        *(float4*)&lt[kl][n4] = *(const float4*)(src + (size_t)kl * H_ + ncol0 + n4);
      }
    }
    __syncthreads();
#pragma unroll
    for (int i = 0; i < 4; ++i) {
      const int idx4 = t + 256 * i;
      const int nl = idx4 >> 4;
      const int k4 = (idx4 & 15) * 4;
      ushort4 h, l;
      const float v0 = lt[k4 + 0][nl], v1 = lt[k4 + 1][nl];
      const float v2 = lt[k4 + 2][nl], v3 = lt[k4 + 3][nl];
      h.x = f2bf(v0); l.x = f2bf(v0 - bf2f(h.x));
      h.y = f2bf(v1); l.y = f2bf(v1 - bf2f(h.y));
      h.z = f2bf(v2); l.z = f2bf(v2 - bf2f(h.z));
      h.w = f2bf(v3); l.w = f2bf(v3 - bf2f(h.w));
      *(ushort4*)(dhi + (size_t)(n0 + nl) * dstride + k0 + k4) = h;
      *(ushort4*)(dlo + (size_t)(n0 + nl) * dstride + k0 + k4) = l;
    }
  } else {
    // histogram: Cm[b][48][64], rows 0..31 = idx2 counts/32 per f, row 32 = idx1 counts/32
    const int b = blk - 320;
    unsigned int* cnt = (unsigned int*)smem;  // [33][64] = 2112
#pragma unroll
    for (int i = 0; i < 9; ++i) { const int p = t + 256 * i; if (p < 2112) cnt[p] = 0u; }
    __syncthreads();
#pragma unroll
    for (int i = 0; i < 4; ++i) {
      const int j = t + 256 * i;  // 0..1023, f = j>>5
      atomicAdd(&cnt[(j >> 5) * 64 + idx2[(size_t)b * 1024 + j]], 1u);
    }
    if (t < 32) atomicAdd(&cnt[32 * 64 + idx1[b * F_ + t]], 1u);
    __syncthreads();
#pragma unroll
    for (int i = 0; i < 12; ++i) {
      const int p = t + 256 * i;  // 0..3071
      Cm[(size_t)b * 3072 + p] = (p < 2112) ? f2bf((float)cnt[p] * 0.03125f) : (unsigned short)0;
    }
  }
}

// ---------------- Kernel 2: fused layer-1 ----------------
// Block (b, s): computes Ys = x_b @ Ws0[:,strip] and Ya = x_b @ Wa0[:,strip]
// (one MFMA GEMM, BM=64 BN=128, K=512, 3-term hi/lo), spills Ys (fp32) and
// Ya^T (hi/lo) to LDS, then count-GEMM C_b @ Ya, then epilogue:
// h1 = leaky(Ys[idx1-row] + m + b0), mean over f -> hm[b][512+col];
// h0 = leaky(Ys[0] + m0 + b0) -> hm[b][col].
__global__ __launch_bounds__(256) void fused1(
    const unsigned short* __restrict__ Xhi, const unsigned short* __restrict__ Xlo,
    const unsigned short* __restrict__ W0thi, const unsigned short* __restrict__ W0tlo,
    const unsigned short* __restrict__ Cm, const int* __restrict__ idx1,
    const float* __restrict__ b0, unsigned short* __restrict__ Hhi,
    unsigned short* __restrict__ Hlo) {
  __shared__ __align__(16) unsigned short lds[24576];  // 48 KB; reused in epilogue
  const int tid = threadIdx.x;
  const int lane = tid & 63;
  const int w = tid >> 6;
  const int wr = w >> 1, wc = w & 1;
  const int lr = lane & 15;
  const int kb = lane >> 4;       // 0..3
  const int rl = lane >> 3;       // 0..7 (row-within-8 for staging)
  const int cbs = ((lane & 7) ^ rl) * 8;  // pre-swizzled k-offset (shorts)

  // XCD-chunk swizzle: 512 blocks = 8 XCDs x (8 b x 8 strips)
  const int o = blockIdx.x;
  const int b = (o & 7) * 8 + (o >> 6);
  const int s = (o >> 3) & 7;

  f32x4 acc[2][4] = {};

  // LDS plane bases (shorts): Ah 0, Al 4096, Bh 8192 ([128][64]), Bl 16384
  for (int kt = 0; kt < 8; ++kt) {
    const int kcol = kt * 64 + cbs;
#pragma unroll
    for (int i = 0; i < 12; ++i) {
      const int slot = w * 12 + i;
      const unsigned short* gp;
      int ldsoff;
      if (slot < 8) {
        gp = Xhi + (size_t)(b * 64 + slot * 8 + rl) * 512 + kcol;
        ldsoff = slot * 512;
      } else if (slot < 16) {
        const int u = slot - 8;
        gp = Xlo + (size_t)(b * 64 + u * 8 + rl) * 512 + kcol;
        ldsoff = 4096 + u * 512;
      } else if (slot < 32) {
        const int u = slot - 16;
        const int row = (u >= 8 ? 512 : 0) + s * 64 + (u & 7) * 8 + rl;
        gp = W0thi + (size_t)row * 512 + kcol;
        ldsoff = 8192 + u * 512;
      } else {
        const int u = slot - 32;
        const int row = (u >= 8 ? 512 : 0) + s * 64 + (u & 7) * 8 + rl;
        gp = W0tlo + (size_t)row * 512 + kcol;
        ldsoff = 16384 + u * 512;
      }
      GLOAD16(gp, &lds[ldsoff]);
    }
    __syncthreads();  // compiler drains vmcnt before barrier -> LDS data landed

#define FRG(base, row, CB) \
  (*(const bf16x8*)&lds[(base) + (row) * 64 + (((CB) ^ (lr & 7)) * 8)])
#pragma unroll
    for (int ks = 0; ks < 2; ++ks) {
      const int CB = ks * 4 + kb;
      const bf16x8 Ah0 = FRG(0, wr * 32 + lr, CB);
      const bf16x8 Ah1 = FRG(0, wr * 32 + 16 + lr, CB);
      const bf16x8 Al0 = FRG(4096, wr * 32 + lr, CB);
      const bf16x8 Al1 = FRG(4096, wr * 32 + 16 + lr, CB);
#pragma unroll
      for (int ni = 0; ni < 4; ++ni) {
        const int brow = wc * 64 + ni * 16 + lr;
        const bf16x8 Bh = FRG(8192, brow, CB);
        const bf16x8 Bl = FRG(16384, brow, CB);
        acc[0][ni] = __builtin_amdgcn_mfma_f32_16x16x32_bf16(Ah0, Bh, acc[0][ni], 0, 0, 0);
        acc[0][ni] = __builtin_amdgcn_mfma_f32_16x16x32_bf16(Ah0, Bl, acc[0][ni], 0, 0, 0);
        acc[0][ni] = __builtin_amdgcn_mfma_f32_16x16x32_bf16(Al0, Bh, acc[0][ni], 0, 0, 0);
        acc[1][ni] = __builtin_amdgcn_mfma_f32_16x16x32_bf16(Ah1, Bh, acc[1][ni], 0, 0, 0);
        acc[1][ni] = __builtin_amdgcn_mfma_f32_16x16x32_bf16(Ah1, Bl, acc[1][ni], 0, 0, 0);
        acc[1][ni] = __builtin_amdgcn_mfma_f32_16x16x32_bf16(Al1, Bh, acc[1][ni], 0, 0, 0);
      }
    }
#undef FRG
    __syncthreads();
  }

  // ---- spill tiles to LDS (reuse) ----
  float* Ysf = (float*)lds;                                    // [64][68] fp32
  unsigned short* Yh = (unsigned short*)((char*)lds + 17408);  // [64 c][72] Ya^T hi
  unsigned short* Yl = Yh + 64 * 72;                           // lo

  if (wc == 0) {  // self half -> Ys (fp32)
#pragma unroll
    for (int mi = 0; mi < 2; ++mi)
#pragma unroll
      for (int ni = 0; ni < 4; ++ni)
#pragma unroll
        for (int r = 0; r < 4; ++r) {
          const int row = wr * 32 + mi * 16 + kb * 4 + r;
          const int c = ni * 16 + lr;
          Ysf[row * 68 + c] = acc[mi][ni][r];
        }
  } else {  // aggr half -> Ya^T hi/lo
#pragma unroll
    for (int mi = 0; mi < 2; ++mi)
#pragma unroll
      for (int ni = 0; ni < 4; ++ni)
#pragma unroll
        for (int r = 0; r < 4; ++r) {
          const int row = wr * 32 + mi * 16 + kb * 4 + r;
          const int c = ni * 16 + lr;
          const float v = acc[mi][ni][r];
          const unsigned short h = f2bf(v);
          Yh[c * 72 + row] = h;
          Yl[c * 72 + row] = f2bf(v - bf2f(h));
        }
  }
  __syncthreads();

  // ---- count-GEMM: macc[f][c] = (C_b/32) @ Ya ----
  bf16x8 Af[3][2];
#pragma unroll
  for (int mi = 0; mi < 3; ++mi)
#pragma unroll
    for (int kf = 0; kf < 2; ++kf)
      Af[mi][kf] = *(const bf16x8*)(Cm + (size_t)b * 3072 + (mi * 16 + lr) * 64 + kf * 32 + kb * 8);

  f32x4 macc[3] = {};
#pragma unroll
  for (int kf = 0; kf < 2; ++kf) {
    const bf16x8 Bh8 = *(const bf16x8*)&Yh[(w * 16 + lr) * 72 + kf * 32 + kb * 8];
    const bf16x8 Bl8 = *(const bf16x8*)&Yl[(w * 16 + lr) * 72 + kf * 32 + kb * 8];
#pragma unroll
    for (int mi = 0; mi < 3; ++mi) {
      macc[mi] = __builtin_amdgcn_mfma_f32_16x16x32_bf16(Af[mi][kf], Bh8, macc[mi], 0, 0, 0);
      macc[mi] = __builtin_amdgcn_mfma_f32_16x16x32_bf16(Af[mi][kf], Bl8, macc[mi], 0, 0, 0);
    }
  }

  // ---- epilogue: h1, mean over f, h0 ----
  const int c = w * 16 + lr;            // local col in strip
  const float bias = b0[s * 64 + c];
  float sum = 0.f;
#pragma unroll
  for (int mi = 0; mi < 2; ++mi)
#pragma unroll
    for (int r = 0; r < 4; ++r) {
      const int f = mi * 16 + kb * 4 + r;       // 0..31
      const int xr = idx1[b * F_ + f];          // gather row in x_b
      sum += leaky(Ysf[xr * 68 + c] + macc[mi][r] + bias);
    }
  sum += __shfl_xor(sum, 16);
  sum += __shfl_xor(sum, 32);
  sum *= (1.0f / 32.0f);
  if (lane < 16) {  // kb==0 lanes: hold macc[2][0] = f=32 (idx1 histogram row)
    unsigned short h = f2bf(sum);
    Hhi[(size_t)b * 1024 + 512 + s * 64 + c] = h;
    Hlo[(size_t)b * 1024 + 512 + s * 64 + c] = f2bf(sum - bf2f(h));
    const float v0 = leaky(Ysf[c] + macc[2][0] + bias);  // Ys row 0 = f0
    const unsigned short h0h = f2bf(v0);
    Hhi[(size_t)b * 1024 + s * 64 + c] = h0h;
    Hlo[(size_t)b * 1024 + s * 64 + c] = f2bf(v0 - bf2f(h0h));
  }
}

// ---------------- Kernel 3: gemm2 split-K partials (unchanged R7) -----------
__global__ __launch_bounds__(256) void gemm2(
    const unsigned short* __restrict__ Hhi, const unsigned short* __restrict__ Hlo,
    const unsigned short* __restrict__ Wthi, const unsigned short* __restrict__ Wtlo,
    float* __restrict__ part) {
  __shared__ float sacc[256][17];
  const int tid = threadIdx.x;
  const int w = tid >> 6;
  const int lane = tid & 63;
  const int lr = lane & 15;
  const int kb = lane >> 4;
  const int n0 = blockIdx.x * 16;
  const int kc = blockIdx.y * 128;

  f32x4 acc[4] = {};
  const int k = kc + w * 32 + kb * 8;
  const bf16x8 Bh = *(const bf16x8*)(Wthi + (size_t)(n0 + lr) * 1024 + k);
  const bf16x8 Bl = *(const bf16x8*)(Wtlo + (size_t)(n0 + lr) * 1024 + k);
#pragma unroll
  for (int mi = 0; mi < 4; ++mi) {
    const bf16x8 Ah = *(const bf16x8*)(Hhi + (size_t)(mi * 16 + lr) * 1024 + k);
    const bf16x8 Al = *(const bf16x8*)(Hlo + (size_t)(mi * 16 + lr) * 1024 + k);
    acc[mi] = __builtin_amdgcn_mfma_f32_16x16x32_bf16(Ah, Bh, acc[mi], 0, 0, 0);
    acc[mi] = __builtin_amdgcn_mfma_f32_16x16x32_bf16(Ah, Bl, acc[mi], 0, 0, 0);
    acc[mi] = __builtin_amdgcn_mfma_f32_16x16x32_bf16(Al, Bh, acc[mi], 0, 0, 0);
  }
#pragma unroll
  for (int mi = 0; mi < 4; ++mi)
#pragma unroll
    for (int r = 0; r < 4; ++r)
      sacc[((w * 4 + mi) * 4 + kb) * 4 + r][lr] = acc[mi][r];
  __syncthreads();

  const int lr2 = tid & 15;
  const int rg = tid >> 4;
  float* pp = part + (size_t)blockIdx.y * (B_ * H_);
#pragma unroll
  for (int q = 0; q < 4; ++q) {
    const int row = rg * 4 + q;
    const int mi = row >> 4, kb2 = (row >> 2) & 3, r = row & 3;
    float s = 0.f;
#pragma unroll
    for (int w2 = 0; w2 < 4; ++w2)
      s += sacc[((w2 * 4 + mi) * 4 + kb2) * 4 + r][lr2];
    pp[(size_t)row * H_ + n0 + lr2] = s;
  }
}

// ---------------- Kernel 4: out = sum_k part + b1 ---------------------------
__global__ __launch_bounds__(256) void reduce_out(
    const float* __restrict__ part, const float* __restrict__ b1,
    float* __restrict__ out) {
  const int idx = blockIdx.x * 256 + threadIdx.x;
  const int c4 = (idx & 127) * 4;
  const size_t off = (size_t)(idx >> 7) * H_ + c4;
  float4 s = *(const float4*)(b1 + c4);
#pragma unroll
  for (int ky = 0; ky < 8; ++ky) {
    const float4 p = *(const float4*)(part + (size_t)ky * (B_ * H_) + off);
    s.x += p.x; s.y += p.y; s.z += p.z; s.w += p.w;
  }
  *(float4*)(out + off) = s;
}

extern "C" void kernel_launch(void* const* d_in, const int* in_sizes, int n_in,
                              void* d_out, int out_size, void* d_ws, size_t ws_size,
                              hipStream_t stream) {
  const float* x    = (const float*)d_in[0];
  const int*   idx1 = (const int*)d_in[1];
  const int*   idx2 = (const int*)d_in[2];
  const float* Wa0  = (const float*)d_in[3];
  const float* b0   = (const float*)d_in[4];
  const float* Ws0  = (const float*)d_in[5];
  const float* Wa1  = (const float*)d_in[6];
  const float* b1   = (const float*)d_in[7];
  const float* Ws1  = (const float*)d_in[8];
  float* out = (float*)d_out;

  unsigned short* wsu = (unsigned short*)d_ws;
  unsigned short* Xhi   = wsu;                          // 4096*512
  unsigned short* Xlo   = Xhi + (size_t)4096 * 512;
  unsigned short* W0thi = Xlo + (size_t)4096 * 512;     // [1024][512]
  unsigned short* W0tlo = W0thi + (size_t)1024 * 512;
  unsigned short* W1thi = W0tlo + (size_t)1024 * 512;   // [512][1024]
  unsigned short* W1tlo = W1thi + (size_t)512 * 1024;
  unsigned short* CmP   = W1tlo + (size_t)512 * 1024;   // 64*48*64
  unsigned short* Hhi   = CmP + (size_t)64 * 3072;      // [64][1024]
  unsigned short* Hlo   = Hhi + (size_t)B_ * 1024;
  float* part = (float*)(Hlo + (size_t)B_ * 1024);      // 8*64*512 fp32

  prep<<<384, 256, 0, stream>>>(x, idx1, idx2, Ws0, Wa0, Ws1, Wa1,
                                Xhi, Xlo, W0thi, W0tlo, W1thi, W1tlo, CmP);
  fused1<<<512, 256, 0, stream>>>(Xhi, Xlo, W0thi, W0tlo, CmP, idx1, b0, Hhi, Hlo);
  gemm2<<<dim3(32, 8), 256, 0, stream>>>(Hhi, Hlo, W1thi, W1tlo, part);
  reduce_out<<<32, 256, 0, stream>>>(part, b1, out);
}